// Round 5
// baseline (176.293 us; speedup 1.0000x reference)
//
#include <hip/hip_runtime.h>
#include <math.h>
#include <stdint.h>

constexpr int B  = 32;
constexpr int C  = 9;
constexpr int NA = 65440;
constexpr int BLOCK = 256;
constexpr int SPAN  = 512;                    // anchors per block
constexpr int BPB   = (NA + SPAN - 1) / SPAN; // 128 blocks per batch (last is partial: 416)
constexpr int GRID  = B * BPB;                // 4096

// LDS float-index layout (one 44 KB buffer, contiguous in DMA order):
//   confs  [c*512 + j]          at    0 .. 4608   (18 chunks of 256 floats)
//   delta  [c*512 + j]          at 4608 .. 6656   ( 8 chunks)
//   gt     [j*4 + k]            at 6656 .. 8704   ( 8 chunks)
//   anch   [c*512 + j]          at 8704 .. 10752  ( 8 chunks)
//   labels [j] (int bits)       at 10752 .. 11264 ( 2 chunks)
constexpr int LDS_FLOATS = 11264;             // 45056 B
constexpr int NCHUNK = 44;                    // 44 x 1KB chunks

// ws partials: focal [0,4096), reg [4096,8192), pos [8192,12288)
constexpr int WS_REG = 4096;
constexpr int WS_POS = 8192;
constexpr size_t WS_NEEDED = (size_t)(WS_POS + 4096) * sizeof(float);

__device__ __forceinline__ void g2lds16(const float* g, float* l) {
    // async DMA global->LDS, 16 B per lane; no VGPR return path, deep queue.
    __builtin_amdgcn_global_load_lds(
        (const __attribute__((address_space(1))) unsigned int*)(uintptr_t)g,
        (__attribute__((address_space(3))) unsigned int*)(uintptr_t)l,
        16, 0, 0);
}

__device__ __forceinline__ float smooth_l1(float d) {
    float ad = fabsf(d);
    return ad < 1.0f ? 0.5f * d * d : ad - 0.5f;
}

template <bool ATOMIC>
__global__ __launch_bounds__(BLOCK, 2) void ssd_main(
    const float* __restrict__ bbox_delta,  // (B,4,NA)
    const float* __restrict__ confs,       // (B,C,NA)
    const float* __restrict__ gt_bbox,     // (B,NA,4)
    const int*   __restrict__ gt_labels,   // (B,NA)
    const float* __restrict__ anchors,     // (1,4,NA)
    float* __restrict__ ws)
{
    __shared__ float lds[LDS_FLOATS];
    __shared__ float sf[4], sr[4], sp[4];

    const int bb  = blockIdx.x >> 7;     // batch
    const int blk = blockIdx.x & 127;    // window within batch
    const int a0  = blk * SPAN;          // first anchor of window
    const int wave = threadIdx.x >> 6;
    const int lane = threadIdx.x & 63;

    // ---------------- stage 44 KB via async DMA: 11 chunk-loads per wave ----------------
#pragma unroll
    for (int i = 0; i < 11; ++i) {
        const int q = wave + (i << 2);   // chunk id, wave-uniform
        const float* src;
        int ebase, lim;
        if (q < 18) {                     // confs plane c, half h
            int c = q >> 1, h = q & 1;
            src = confs; ebase = bb * C * NA + c * NA + a0 + h * 256; lim = B * C * NA;
        } else if (q < 26) {              // bbox_delta
            int r = q - 18; int c = r >> 1, h = r & 1;
            src = bbox_delta; ebase = bb * 4 * NA + c * NA + a0 + h * 256; lim = B * 4 * NA;
        } else if (q < 34) {              // gt_bbox (contiguous j*4+k)
            int r = q - 26;
            src = gt_bbox; ebase = (bb * NA + a0) * 4 + r * 256; lim = B * NA * 4;
        } else if (q < 42) {              // anchors
            int r = q - 34; int c = r >> 1, h = r & 1;
            src = anchors; ebase = c * NA + a0 + h * 256; lim = 4 * NA;
        } else {                          // labels (int bits through float path)
            int r = q - 42;
            src = (const float*)gt_labels; ebase = bb * NA + a0 + r * 256; lim = B * NA;
        }
        int e = ebase + lane * 4;
        e = (e > lim - 4) ? (lim - 4) : e;   // clamp: tail windows stay in-bounds
        g2lds16(src + e, &lds[q * 256 + lane * 4]);
    }
    __syncthreads();   // compiler emits s_waitcnt vmcnt(0) before s_barrier -> DMA complete

    // ---------------- compute: 2 anchors per thread, all data from LDS ----------------
    const int t = threadIdx.x;
    float focal = 0.f, reg = 0.f, pcnt = 0.f;

    float2 cf2[C];
#pragma unroll
    for (int c = 0; c < C; ++c) cf2[c] = *(const float2*)&lds[c * 512 + 2 * t];
    float2 dd[4];
#pragma unroll
    for (int c = 0; c < 4; ++c) dd[c] = *(const float2*)&lds[4608 + c * 512 + 2 * t];
    const float4 gA = *(const float4*)&lds[6656 + (2 * t) * 4];
    const float4 gB = *(const float4*)&lds[6656 + (2 * t + 1) * 4];
    float2 aa[4];
#pragma unroll
    for (int c = 0; c < 4; ++c) aa[c] = *(const float2*)&lds[8704 + c * 512 + 2 * t];
    const int2 lb = *(const int2*)((const int*)lds + 10752 + 2 * t);

#pragma unroll
    for (int jj = 0; jj < 2; ++jj) {
        const bool valid = (a0 + 2 * t + jj) < NA;
        const int lab = jj ? lb.y : lb.x;
        // classification: single-pass logsumexp (inputs ~N(0,1), no overflow)
        float se = 0.f, ct = cf2[0].x, pe = 0.f;
#pragma unroll
        for (int c = 0; c < C; ++c) {
            const float cv = jj ? cf2[c].y : cf2[c].x;
            const float e = __expf(cv);
            se += e;
            if (lab == c) { ct = cv; pe = e; }
        }
        const float lp = ct - __logf(se);
        const float p  = __fdividef(pe, se);
        const float o  = 1.f - p;
        const float v  = valid ? 1.f : 0.f;
        focal += v * (o * o * o * lp);
        // regression
        const float4 g = jj ? gB : gA;
        const float ax = jj ? aa[0].y : aa[0].x;
        const float ay = jj ? aa[1].y : aa[1].x;
        const float aw = jj ? aa[2].y : aa[2].x;
        const float ah = jj ? aa[3].y : aa[3].x;
        const float d0 = jj ? dd[0].y : dd[0].x;
        const float d1 = jj ? dd[1].y : dd[1].x;
        const float d2 = jj ? dd[2].y : dd[2].x;
        const float d3 = jj ? dd[3].y : dd[3].x;
        const float gx = 10.0f * __fdividef(g.x - ax, aw);
        const float gy = 10.0f * __fdividef(g.y - ay, ah);
        const float gw = 5.0f * __logf(__fdividef(g.z, aw));
        const float gh = 5.0f * __logf(__fdividef(g.w, ah));
        const float s  = smooth_l1(d0 - gx) + smooth_l1(d1 - gy) +
                         smooth_l1(d2 - gw) + smooth_l1(d3 - gh);
        const float ps = (valid && lab > 0) ? 1.f : 0.f;
        reg  += ps * s;
        pcnt += ps;
    }

    // ---------------- reduction: wave shuffle -> LDS -> 1 write/atomic per block ----------------
#pragma unroll
    for (int off = 32; off > 0; off >>= 1) {
        focal += __shfl_down(focal, off, 64);
        reg   += __shfl_down(reg,   off, 64);
        pcnt  += __shfl_down(pcnt,  off, 64);
    }
    if (lane == 0) { sf[wave] = focal; sr[wave] = reg; sp[wave] = pcnt; }
    __syncthreads();
    if (t == 0) {
        const float F = sf[0] + sf[1] + sf[2] + sf[3];
        const float R = sr[0] + sr[1] + sr[2] + sr[3];
        const float P = sp[0] + sp[1] + sp[2] + sp[3];
        if (ATOMIC) {
            atomicAdd(&ws[0],  F);
            atomicAdd(&ws[32], R);
            atomicAdd(&ws[64], P);
        } else {
            ws[blockIdx.x]          = F;
            ws[WS_REG + blockIdx.x] = R;
            ws[WS_POS + blockIdx.x] = P;
        }
    }
}

__global__ void zero_ws_k(float* ws) {
    int i = threadIdx.x;
    if (i < 96) ws[i] = 0.0f;
}

__global__ void finalize_atomic_k(const float* __restrict__ ws, float* __restrict__ out) {
    const float inv_n = 1.0f / (float)((size_t)B * NA);
    out[0] = ws[32] / ws[64] - 8010.0f * ws[0] * inv_n;
}

__global__ __launch_bounds__(256) void finalize_k(const float* __restrict__ ws,
                                                  float* __restrict__ out) {
    float F = 0.f, R = 0.f, P = 0.f;
    for (int i = threadIdx.x; i < GRID; i += 256) {
        F += ws[i];
        R += ws[WS_REG + i];
        P += ws[WS_POS + i];
    }
#pragma unroll
    for (int off = 32; off > 0; off >>= 1) {
        F += __shfl_down(F, off, 64);
        R += __shfl_down(R, off, 64);
        P += __shfl_down(P, off, 64);
    }
    __shared__ float sf[4], sr[4], sp[4];
    const int wid  = threadIdx.x >> 6;
    const int lane = threadIdx.x & 63;
    if (lane == 0) { sf[wid] = F; sr[wid] = R; sp[wid] = P; }
    __syncthreads();
    if (threadIdx.x == 0) {
        const float Ft = sf[0] + sf[1] + sf[2] + sf[3];
        const float Rt = sr[0] + sr[1] + sr[2] + sr[3];
        const float Pt = sp[0] + sp[1] + sp[2] + sp[3];
        // sum(alpha) = 10 + 8*1000 = 8010 ; classification = mean(-8010 * focal)
        const float inv_n = 1.0f / (float)((size_t)B * NA);
        out[0] = Rt / Pt - 8010.0f * Ft * inv_n;
    }
}

extern "C" void kernel_launch(void* const* d_in, const int* in_sizes, int n_in,
                              void* d_out, int out_size, void* d_ws, size_t ws_size,
                              hipStream_t stream) {
    const float* bbox_delta = (const float*)d_in[0];
    const float* confs      = (const float*)d_in[1];
    const float* gt_bbox    = (const float*)d_in[2];
    const int*   gt_labels  = (const int*)d_in[3];
    const float* anchors    = (const float*)d_in[4];
    float* ws  = (float*)d_ws;
    float* out = (float*)d_out;

    if (ws_size >= WS_NEEDED) {
        ssd_main<false><<<GRID, BLOCK, 0, stream>>>(bbox_delta, confs, gt_bbox,
                                                    gt_labels, anchors, ws);
        finalize_k<<<1, 256, 0, stream>>>(ws, out);
    } else {
        zero_ws_k<<<1, 128, 0, stream>>>(ws);
        ssd_main<true><<<GRID, BLOCK, 0, stream>>>(bbox_delta, confs, gt_bbox,
                                                   gt_labels, anchors, ws);
        finalize_atomic_k<<<1, 1, 0, stream>>>(ws, out);
    }
}